// Round 1
// baseline (238.907 us; speedup 1.0000x reference)
//
#include <hip/hip_runtime.h>

// GAT forward on MI355X.
// N=4096 nodes, IN_F=512, OUT_F=64, HEADS=4, alpha=0.2.
//
// Pipeline:
//   gemm_hT : h = x@W via bf16 MFMA, written TRANSPOSED as bf16: Vt[n][i], n=head*64+f
//   gat_prep: s,t per (node,head) from Vt; store (e^s, e^{0.2s}) and (e^t, e^{0.2t})
//   gat_attn: fused masked-softmax + attn@h. Scores are rank-1: e=LR(s_i+t_j);
//             exp(LR(u)) = es*et if es*et>1 else eas*eat  (no exp in hot loop).
//             P built directly in MFMA A-fragment layout; V read as contiguous
//             16B B-fragments from Vt. l = rowsum(P) via VALU + shuffle reduce.

#define NN 4096
#define KF 512
#define NF 256   // HEADS*OUT_F

typedef __attribute__((ext_vector_type(8))) short bf16x8;
typedef __attribute__((ext_vector_type(4))) short s16x4;
typedef __attribute__((ext_vector_type(4))) float f32x4;

__device__ inline short f2bf(float f) {
    union { float f; unsigned u; } v; v.f = f;
    unsigned r = v.u + 0x7fffu + ((v.u >> 16) & 1u);  // RNE (finite inputs only)
    return (short)(r >> 16);
}
__device__ inline float bf2f(short b) {
    union { unsigned u; float f; } v;
    v.u = ((unsigned)(unsigned short)b) << 16;
    return v.f;
}

// ---------------- Kernel A: h = x@W, stored as hT in bf16 ----------------
// grid (64,4), block 256 (4 waves). Wave computes 16 rows x 64 cols.
__global__ __launch_bounds__(256) void gemm_hT(const float* __restrict__ x,
                                               const float* __restrict__ W,
                                               short* __restrict__ Vt) {
    const int lane = threadIdx.x & 63;
    const int wv   = threadIdx.x >> 6;
    const int q = lane >> 4, r = lane & 15;
    const int i0 = blockIdx.x * 64 + wv * 16;   // M base for this wave
    const int n0 = blockIdx.y * 64;             // N base for this block

    f32x4 acc[4] = {};
    for (int k0 = 0; k0 < KF; k0 += 32) {
        // A-fragment: x[i0+r][k0+q*8 .. +7], contiguous fp32 -> bf16
        const float* xp = x + (i0 + r) * KF + k0 + q * 8;
        float4 xa = *(const float4*)xp;
        float4 xb = *(const float4*)(xp + 4);
        bf16x8 af;
        af[0]=f2bf(xa.x); af[1]=f2bf(xa.y); af[2]=f2bf(xa.z); af[3]=f2bf(xa.w);
        af[4]=f2bf(xb.x); af[5]=f2bf(xb.y); af[6]=f2bf(xb.z); af[7]=f2bf(xb.w);
        #pragma unroll
        for (int nt = 0; nt < 4; nt++) {
            // B-fragment: W[k0+q*8+jj][n0+nt*16+r]  (column reads, L2-resident W)
            const float* wp = W + (k0 + q * 8) * NF + n0 + nt * 16 + r;
            bf16x8 bv;
            #pragma unroll
            for (int jj = 0; jj < 8; jj++) bv[jj] = f2bf(wp[jj * NF]);
            acc[nt] = __builtin_amdgcn_mfma_f32_16x16x32_bf16(af, bv, acc[nt], 0, 0, 0);
        }
    }
    // C/D layout: lane holds D[row=q*4+reg][col=r]. Write transposed: Vt[n][i].
    // 4 regs = 4 consecutive i -> one 8B store.
    #pragma unroll
    for (int nt = 0; nt < 4; nt++) {
        int n = n0 + nt * 16 + r;
        s16x4 sv;
        sv[0]=f2bf(acc[nt][0]); sv[1]=f2bf(acc[nt][1]);
        sv[2]=f2bf(acc[nt][2]); sv[3]=f2bf(acc[nt][3]);
        *(s16x4*)(Vt + n * NN + i0 + q * 4) = sv;
    }
}

// ---------------- Kernel B: per-node (e^s, e^{0.2s}), (e^t, e^{0.2t}) ----------------
// grid (16,4), block 256. thread: node n, head = blockIdx.y.
__global__ __launch_bounds__(256) void gat_prep(const short* __restrict__ Vt,
                                                const float* __restrict__ a,
                                                float2* __restrict__ ipack,
                                                float2* __restrict__ jpack) {
    int n  = blockIdx.x * 256 + threadIdx.x;
    int hd = blockIdx.y;
    float s = 0.f, t = 0.f;
    #pragma unroll 8
    for (int f = 0; f < 64; f++) {
        float v = bf2f(Vt[(hd * 64 + f) * NN + n]);
        s += v * a[f];
        t += v * a[64 + f];
    }
    ipack[hd * NN + n] = make_float2(__expf(s), __expf(0.2f * s));
    jpack[hd * NN + n] = make_float2(__expf(t), __expf(0.2f * t));
}

// ---------------- Kernel C: fused masked softmax + attn@h ----------------
// grid 256, block 512 (8 waves): wave = (jhalf<<2)|head. 16 i-rows per block.
__global__ __launch_bounds__(512) void gat_attn(const int* __restrict__ adj,
                                                const float2* __restrict__ ipack,
                                                const float2* __restrict__ jpack,
                                                const short* __restrict__ Vt,
                                                float* __restrict__ out) {
    const int tid  = threadIdx.x;
    const int lane = tid & 63;
    const int wv   = tid >> 6;
    const int hd   = wv & 3;
    const int jh   = wv >> 2;            // 0 or 1: which j-half
    const int q = lane >> 4, r = lane & 15;
    const int i0 = blockIdx.x * 16;
    const int i  = i0 + r;

    const float2 ip = ipack[hd * NN + i];   // (e^{s_i}, e^{0.2 s_i})

    f32x4 acc[4] = {};
    float lsum = 0.f;

    const int jbeg = jh * (NN / 2);
    const int jend = jbeg + (NN / 2);
    const float* jpf = (const float*)(jpack + hd * NN);

    for (int j0 = jbeg; j0 < jend; j0 += 32) {
        const int kb = j0 + q * 8;        // this lane's k-range base (8 j's)
        const int4* ap = (const int4*)(adj + (size_t)i * NN + kb);
        int4 a0 = ap[0];
        int4 a1 = ap[1];
        const float4* jp = (const float4*)(jpf + 2 * kb);
        float4 j0v = jp[0], j1v = jp[1], j2v = jp[2], j3v = jp[3];

        float p[8];
        {
            // p = adj ? (es*et > 1 ? es*et : eas*eat) : 0   == adj ? exp(LR(s+t)) : 0
            float pe, pa;
            pe = ip.x * j0v.x; pa = ip.y * j0v.y; p[0] = a0.x ? (pe > 1.f ? pe : pa) : 0.f;
            pe = ip.x * j0v.z; pa = ip.y * j0v.w; p[1] = a0.y ? (pe > 1.f ? pe : pa) : 0.f;
            pe = ip.x * j1v.x; pa = ip.y * j1v.y; p[2] = a0.z ? (pe > 1.f ? pe : pa) : 0.f;
            pe = ip.x * j1v.z; pa = ip.y * j1v.w; p[3] = a0.w ? (pe > 1.f ? pe : pa) : 0.f;
            pe = ip.x * j2v.x; pa = ip.y * j2v.y; p[4] = a1.x ? (pe > 1.f ? pe : pa) : 0.f;
            pe = ip.x * j2v.z; pa = ip.y * j2v.w; p[5] = a1.y ? (pe > 1.f ? pe : pa) : 0.f;
            pe = ip.x * j3v.x; pa = ip.y * j3v.y; p[6] = a1.z ? (pe > 1.f ? pe : pa) : 0.f;
            pe = ip.x * j3v.z; pa = ip.y * j3v.w; p[7] = a1.w ? (pe > 1.f ? pe : pa) : 0.f;
        }
        lsum += ((p[0] + p[1]) + (p[2] + p[3])) + ((p[4] + p[5]) + (p[6] + p[7]));

        bf16x8 af;
        #pragma unroll
        for (int e = 0; e < 8; e++) af[e] = f2bf(p[e]);

        #pragma unroll
        for (int nt = 0; nt < 4; nt++) {
            // B-fragment: Vt[hd*64+nt*16+r][kb .. kb+7] -- contiguous 16B
            const short* vp = Vt + (hd * 64 + nt * 16 + r) * NN + kb;
            bf16x8 bv = *(const bf16x8*)vp;
            acc[nt] = __builtin_amdgcn_mfma_f32_16x16x32_bf16(af, bv, acc[nt], 0, 0, 0);
        }
    }

    // Combine the two j-halves through LDS.
    __shared__ float sacc[4][4][64][4];   // [head][nt][lane][reg]
    __shared__ float slsum[4][64];
    if (jh == 1) {
        #pragma unroll
        for (int nt = 0; nt < 4; nt++)
            *(f32x4*)&sacc[hd][nt][lane][0] = acc[nt];
        slsum[hd][lane] = lsum;
    }
    __syncthreads();
    if (jh == 0) {
        lsum += slsum[hd][lane];
        #pragma unroll
        for (int nt = 0; nt < 4; nt++) {
            f32x4 o = *(const f32x4*)&sacc[hd][nt][lane][0];
            acc[nt][0] += o[0]; acc[nt][1] += o[1];
            acc[nt][2] += o[2]; acc[nt][3] += o[3];
        }
        // lsum is the partial for row r held by lanes {r, r+16, r+32, r+48}
        lsum += __shfl_xor(lsum, 16, 64);
        lsum += __shfl_xor(lsum, 32, 64);
        // output rows for this lane are q*4+reg; pull l from lane (q*4+reg)
        #pragma unroll
        for (int reg = 0; reg < 4; reg++) {
            float lr  = __shfl(lsum, q * 4 + reg, 64);
            float inv = 1.f / lr;
            int row = i0 + q * 4 + reg;
            #pragma unroll
            for (int nt = 0; nt < 4; nt++)
                out[row * NF + hd * 64 + nt * 16 + r] = acc[nt][reg] * inv;
        }
    }
}

extern "C" void kernel_launch(void* const* d_in, const int* in_sizes, int n_in,
                              void* d_out, int out_size, void* d_ws, size_t ws_size,
                              hipStream_t stream) {
    const float* x   = (const float*)d_in[0];
    const int*   adj = (const int*)d_in[1];
    const float* W   = (const float*)d_in[2];
    const float* a   = (const float*)d_in[3];
    float* out = (float*)d_out;

    char* ws = (char*)d_ws;
    short*  Vt    = (short*)ws;                               // 256*4096*2  = 2 MiB
    float2* ipack = (float2*)(ws + 2097152);                  // 4*4096*8    = 128 KiB
    float2* jpack = (float2*)(ws + 2097152 + 131072);         // 4*4096*8    = 128 KiB

    gemm_hT <<<dim3(64, 4), 256, 0, stream>>>(x, W, Vt);
    gat_prep<<<dim3(16, 4), 256, 0, stream>>>(Vt, a, ipack, jpack);
    gat_attn<<<256, 512, 0, stream>>>(adj, ipack, jpack, Vt, out);
}

// Round 3
// 219.177 us; speedup vs baseline: 1.0900x; 1.0900x over previous
//
#include <hip/hip_runtime.h>
#include <hip/hip_bf16.h>

// GAT forward on MI355X. N=4096, IN_F=512, OUT_F=64, HEADS=4, alpha=0.2.
//
// Pipeline (4 dispatches):
//   conv_Wt : W[512][256] fp32 -> Wt[256][512] bf16 (transposed)
//   gemm_hT : h = x@W via bf16 MFMA, stored TRANSPOSED bf16: Vt[n][i], n=head*64+f
//   gat_prep: s,t per (node,head); store (e^s, e^{0.2s}), (e^t, e^{0.2t})
//   gat_attn: fused masked softmax + attn@h. exp(leakyrelu(s+t)) == max(e^s e^t,
//             e^.2s e^.2t) -- no transcendentals in hot loop.
//
// R1 post-mortem: VGPR_Count=32 forced one-load-at-a-time serialization
// (~5300 cyc/iter, all pipes <15%). R2/R3: launch_bounds register budget +
// manual double-buffered prefetch + 16 waves/CU. (R2 had a compile error:
// ext_vector element address; fixed with unions.)

#define NN 4096
#define KF 512
#define NF 256   // HEADS*OUT_F

typedef __attribute__((ext_vector_type(8))) short bf16x8;
typedef __attribute__((ext_vector_type(4))) short s16x4;
typedef __attribute__((ext_vector_type(4))) float f32x4;

union AB8 { bf16x8 v; short2 h[4]; };
union ST4 { s16x4 v; short2 h[2]; };

__device__ __forceinline__ short f2bf(float f) {
    union { float f; unsigned u; } v; v.f = f;
    unsigned r = v.u + 0x7fffu + ((v.u >> 16) & 1u);  // RNE (finite only)
    return (short)(r >> 16);
}
__device__ __forceinline__ float bf2f(short b) {
    union { unsigned u; float f; } v;
    v.u = ((unsigned)(unsigned short)b) << 16;
    return v.f;
}
// packed f32x2 -> bf16x2 (v_cvt_pk_bf16_f32 on gfx950)
__device__ __forceinline__ short2 pkbf(float a, float b) {
    __hip_bfloat162 t = __float22bfloat162_rn(make_float2(a, b));
    union { __hip_bfloat162 v; short2 s; } u; u.v = t;
    return u.s;
}

// ---------------- conv_Wt: W -> Wt bf16 transposed ----------------
__global__ __launch_bounds__(256) void conv_Wt(const float* __restrict__ W,
                                               short* __restrict__ Wt) {
    int idx = blockIdx.x * 256 + threadIdx.x;   // [0, 131072)
    int n = idx >> 9, k = idx & 511;
    Wt[idx] = f2bf(W[k * NF + n]);              // Wt[n][k] = W[k][n]
}

// ---------------- gemm_hT: h = x@W, stored as hT in bf16 ----------------
// grid (64,8), block 256 (4 waves). Wave: 16 i-rows x 32 n-cols (nt=2).
__global__ __launch_bounds__(256, 2) void gemm_hT(const float* __restrict__ x,
                                                  const short* __restrict__ Wt,
                                                  short* __restrict__ Vt) {
    const int lane = threadIdx.x & 63;
    const int wv   = threadIdx.x >> 6;
    const int q = lane >> 4, r = lane & 15;
    const int i0 = blockIdx.x * 64 + wv * 16;
    const int n0 = blockIdx.y * 32;

    const float* xp  = x  + (size_t)(i0 + r) * KF + q * 8;
    const short* wp0 = Wt + (size_t)(n0 + r) * KF + q * 8;
    const short* wp1 = wp0 + 16 * KF;

    f32x4 acc[2] = {};
    #pragma unroll 4
    for (int k0 = 0; k0 < KF; k0 += 32) {
        float4 xa = *(const float4*)xp;
        float4 xb = *(const float4*)(xp + 4);
        AB8 af;
        af.h[0] = pkbf(xa.x, xa.y);
        af.h[1] = pkbf(xa.z, xa.w);
        af.h[2] = pkbf(xb.x, xb.y);
        af.h[3] = pkbf(xb.z, xb.w);
        bf16x8 b0 = *(const bf16x8*)wp0;
        bf16x8 b1 = *(const bf16x8*)wp1;
        acc[0] = __builtin_amdgcn_mfma_f32_16x16x32_bf16(af.v, b0, acc[0], 0, 0, 0);
        acc[1] = __builtin_amdgcn_mfma_f32_16x16x32_bf16(af.v, b1, acc[1], 0, 0, 0);
        xp += 32; wp0 += 32; wp1 += 32;
    }
    // C/D: lane holds D[row=q*4+reg][col=r]; write transposed Vt[n][i] (8B store)
    #pragma unroll
    for (int nt = 0; nt < 2; nt++) {
        int n = n0 + nt * 16 + r;
        ST4 sv;
        sv.h[0] = pkbf(acc[nt][0], acc[nt][1]);
        sv.h[1] = pkbf(acc[nt][2], acc[nt][3]);
        *(s16x4*)(Vt + (size_t)n * NN + i0 + q * 4) = sv.v;
    }
}

// ---------------- gat_prep: (e^s, e^{0.2s}), (e^t, e^{0.2t}) per node/head ----------------
__global__ __launch_bounds__(256) void gat_prep(const short* __restrict__ Vt,
                                                const float* __restrict__ a,
                                                float2* __restrict__ ipack,
                                                float2* __restrict__ jpack) {
    int n  = blockIdx.x * 256 + threadIdx.x;
    int hd = blockIdx.y;
    float s = 0.f, t = 0.f;
    #pragma unroll 8
    for (int f = 0; f < 64; f++) {
        float v = bf2f(Vt[(size_t)(hd * 64 + f) * NN + n]);
        s += v * a[f];
        t += v * a[64 + f];
    }
    ipack[hd * NN + n] = make_float2(__expf(s), __expf(0.2f * s));
    jpack[hd * NN + n] = make_float2(__expf(t), __expf(0.2f * t));
}

// ---------------- gat_attn: fused masked softmax + attn@h ----------------
// grid 256, block 1024 (16 waves): wave = (jquarter<<2)|head. 16 i-rows/block.
struct Frag { int4 a0, a1; float4 j0, j1, j2, j3; };

__device__ __forceinline__ void frag_load(Frag& F, const int* ap, const float* jp) {
    const int4* a = (const int4*)ap;
    F.a0 = a[0]; F.a1 = a[1];
    const float4* j = (const float4*)jp;
    F.j0 = j[0]; F.j1 = j[1]; F.j2 = j[2]; F.j3 = j[3];
}

__global__ __launch_bounds__(1024, 4) void gat_attn(const int* __restrict__ adj,
                                                    const float2* __restrict__ ipack,
                                                    const float2* __restrict__ jpack,
                                                    const short* __restrict__ Vt,
                                                    float* __restrict__ out) {
    const int tid  = threadIdx.x;
    const int lane = tid & 63;
    const int wv   = tid >> 6;
    const int hd   = wv & 3;
    const int jq   = wv >> 2;            // 0..3: j-quarter
    const int q = lane >> 4, r = lane & 15;
    const int i0 = blockIdx.x * 16;
    const int i  = i0 + r;

    const float2 ip = ipack[hd * NN + i];

    const int kb0 = jq * 1024 + q * 8;   // this lane's first 8-j chunk
    const int*   aptr = adj + (size_t)i * NN + kb0;
    const float* jptr = (const float*)(jpack + hd * NN) + 2 * kb0;
    const short* vptr = Vt + (size_t)(hd * 64 + r) * NN + kb0;  // +nt*16*NN per nt

    f32x4 acc[4] = {};
    float lsum = 0.f;

    Frag f0, f1;
    frag_load(f0, aptr, jptr);

    #define CONSUME(F, IT)                                                        \
    {                                                                             \
        const short* vp = vptr + (IT) * 32;                                       \
        bf16x8 bv0 = *(const bf16x8*)(vp);                                        \
        bf16x8 bv1 = *(const bf16x8*)(vp + 16 * NN);                              \
        bf16x8 bv2 = *(const bf16x8*)(vp + 32 * NN);                              \
        bf16x8 bv3 = *(const bf16x8*)(vp + 48 * NN);                              \
        float p0 = (F).a0.x ? fmaxf(ip.x * (F).j0.x, ip.y * (F).j0.y) : 0.f;      \
        float p1 = (F).a0.y ? fmaxf(ip.x * (F).j0.z, ip.y * (F).j0.w) : 0.f;      \
        float p2 = (F).a0.z ? fmaxf(ip.x * (F).j1.x, ip.y * (F).j1.y) : 0.f;      \
        float p3 = (F).a0.w ? fmaxf(ip.x * (F).j1.z, ip.y * (F).j1.w) : 0.f;      \
        float p4 = (F).a1.x ? fmaxf(ip.x * (F).j2.x, ip.y * (F).j2.y) : 0.f;      \
        float p5 = (F).a1.y ? fmaxf(ip.x * (F).j2.z, ip.y * (F).j2.w) : 0.f;      \
        float p6 = (F).a1.z ? fmaxf(ip.x * (F).j3.x, ip.y * (F).j3.y) : 0.f;      \
        float p7 = (F).a1.w ? fmaxf(ip.x * (F).j3.z, ip.y * (F).j3.w) : 0.f;      \
        lsum += ((p0 + p1) + (p2 + p3)) + ((p4 + p5) + (p6 + p7));                \
        AB8 af;                                                                   \
        af.h[0] = pkbf(p0, p1);                                                   \
        af.h[1] = pkbf(p2, p3);                                                   \
        af.h[2] = pkbf(p4, p5);                                                   \
        af.h[3] = pkbf(p6, p7);                                                   \
        acc[0] = __builtin_amdgcn_mfma_f32_16x16x32_bf16(af.v, bv0, acc[0], 0, 0, 0);\
        acc[1] = __builtin_amdgcn_mfma_f32_16x16x32_bf16(af.v, bv1, acc[1], 0, 0, 0);\
        acc[2] = __builtin_amdgcn_mfma_f32_16x16x32_bf16(af.v, bv2, acc[2], 0, 0, 0);\
        acc[3] = __builtin_amdgcn_mfma_f32_16x16x32_bf16(af.v, bv3, acc[3], 0, 0, 0);\
    }

    const int ITER = 32;   // 1024 j / 32 per iter
    for (int it = 0; it < ITER; it += 2) {
        frag_load(f1, aptr + (it + 1) * 32, jptr + (it + 1) * 64);
        CONSUME(f0, it);
        if (it + 2 < ITER)
            frag_load(f0, aptr + (it + 2) * 32, jptr + (it + 2) * 64);
        CONSUME(f1, it + 1);
    }
    #undef CONSUME

    // Combine 4 j-quarters through LDS.
    __shared__ float sacc[3][4][4][64][4];   // [jq-1][head][nt][lane][reg]
    __shared__ float slsum[3][4][64];
    if (jq > 0) {
        const int g = jq - 1;
        #pragma unroll
        for (int nt = 0; nt < 4; nt++)
            *(f32x4*)&sacc[g][hd][nt][lane][0] = acc[nt];
        slsum[g][hd][lane] = lsum;
    }
    __syncthreads();
    if (jq == 0) {
        #pragma unroll
        for (int g = 0; g < 3; g++) {
            lsum += slsum[g][hd][lane];
            #pragma unroll
            for (int nt = 0; nt < 4; nt++) {
                f32x4 o = *(const f32x4*)&sacc[g][hd][nt][lane][0];
                acc[nt][0] += o[0]; acc[nt][1] += o[1];
                acc[nt][2] += o[2]; acc[nt][3] += o[3];
            }
        }
        // row-sum: lanes {r, r+16, r+32, r+48} hold partials for row r
        lsum += __shfl_xor(lsum, 16, 64);
        lsum += __shfl_xor(lsum, 32, 64);
        #pragma unroll
        for (int reg = 0; reg < 4; reg++) {
            float lr  = __shfl(lsum, q * 4 + reg, 64);
            float inv = 1.f / lr;
            int row = i0 + q * 4 + reg;
            #pragma unroll
            for (int nt = 0; nt < 4; nt++)
                out[(size_t)row * NF + hd * 64 + nt * 16 + r] = acc[nt][reg] * inv;
        }
    }
}

extern "C" void kernel_launch(void* const* d_in, const int* in_sizes, int n_in,
                              void* d_out, int out_size, void* d_ws, size_t ws_size,
                              hipStream_t stream) {
    const float* x   = (const float*)d_in[0];
    const int*   adj = (const int*)d_in[1];
    const float* W   = (const float*)d_in[2];
    const float* a   = (const float*)d_in[3];
    float* out = (float*)d_out;

    char* ws = (char*)d_ws;
    short*  Vt    = (short*)ws;                               // 256*4096*2  = 2 MiB
    float2* ipack = (float2*)(ws + 2097152);                  // 128 KiB
    float2* jpack = (float2*)(ws + 2097152 + 131072);         // 128 KiB
    short*  Wt    = (short*)(ws + 2097152 + 262144);          // 256*512*2 = 256 KiB

    conv_Wt <<<512, 256, 0, stream>>>(W, Wt);
    gemm_hT <<<dim3(64, 8), 256, 0, stream>>>(x, Wt, Vt);
    gat_prep<<<dim3(16, 4), 256, 0, stream>>>(Vt, a, ipack, jpack);
    gat_attn<<<256, 1024, 0, stream>>>(adj, ipack, jpack, Vt, out);
}

// Round 4
// 152.190 us; speedup vs baseline: 1.5698x; 1.4402x over previous
//
#include <hip/hip_runtime.h>
#include <hip/hip_bf16.h>

// GAT forward on MI355X. N=4096, IN_F=512, OUT_F=64, HEADS=4, alpha=0.2.
//
// R3 post-mortem: attn was vmem-transaction/latency bound (adj 2x16-line insts,
// Vt 4x16-line insts per iter; compiler squeezed to 56 VGPR). R4 redesign:
//   xcast  : x fp32 -> bf16 (RNE, same numerics as before)
//   wpack  : W -> bf16 MFMA-B-fragment order WtF[kblk][hd][nt][lane][8]
//   adjpack: adj int32 -> bitmask via __ballot, transposed group layout
//            pT[w4][i][4 words]  (67 MB -> 2 MB; the 67 MB read is coalesced)
//   gemm   : h = x@W, epilogue writes h in B-fragment order VtF[jblk][hd][nt][lane][8]
//   prep   : from VtF: c_i = e^{-0.8 s_i} (ipack), (e^t, e^{0.2t}) (jpack)
//   attn   : p = adjbit ? max(et_j, c_i*eat_j) : 0   (softmax scale-invariant
//            factoring of exp(leakyrelu(s+t))); A-frag built in-register,
//            B-frag = dense 1KB VtF loads; rowsum via 5th MFMA with B=ones.

#define NN 4096
#define KF 512
#define NF 256

typedef __attribute__((ext_vector_type(8))) short bf16x8;
typedef __attribute__((ext_vector_type(4))) short s16x4;
typedef __attribute__((ext_vector_type(4))) float f32x4;

union AB8 { bf16x8 v; short2 h[4]; short s[8]; int4 i4; };
union ST4 { s16x4 v; short2 h[2]; };

__device__ __forceinline__ short f2bf(float f) {
    union { float f; unsigned u; } v; v.f = f;
    unsigned r = v.u + 0x7fffu + ((v.u >> 16) & 1u);  // RNE (finite only)
    return (short)(r >> 16);
}
__device__ __forceinline__ float bf2f(short b) {
    union { unsigned u; float f; } v;
    v.u = ((unsigned)(unsigned short)b) << 16;
    return v.f;
}
__device__ __forceinline__ short2 pkbf(float a, float b) {
    __hip_bfloat162 t = __float22bfloat162_rn(make_float2(a, b));
    union { __hip_bfloat162 v; short2 s; } u; u.v = t;
    return u.s;
}

// ---------------- xcast: x fp32 -> bf16 ----------------
__global__ __launch_bounds__(256) void xcast(const float* __restrict__ x,
                                             short* __restrict__ xb) {
    int idx = (blockIdx.x * 256 + threadIdx.x) * 4;
    float4 v = *(const float4*)(x + idx);
    ST4 o; o.h[0] = pkbf(v.x, v.y); o.h[1] = pkbf(v.z, v.w);
    *(s16x4*)(xb + idx) = o.v;
}

// ---------------- wpack: W -> B-fragment order bf16 ----------------
// WtF[kblk(16)][hd(4)][nt(4)][lane(64)][e(8)]; lane=(q,r): W[kblk*32+q*8+e][hd*64+nt*16+r]
__global__ __launch_bounds__(256) void wpack(const float* __restrict__ W,
                                             short* __restrict__ WtF) {
    int tid = blockIdx.x * 256 + threadIdx.x;   // 16384 threads
    int l = tid & 63, nt = (tid >> 6) & 3, hd = (tid >> 8) & 3, kblk = tid >> 10;
    int q = l >> 4, r = l & 15;
    int col = hd * 64 + nt * 16 + r;
    int k0 = kblk * 32 + q * 8;
    AB8 o;
    #pragma unroll
    for (int e = 0; e < 8; e++) o.s[e] = f2bf(W[(k0 + e) * NF + col]);
    *(bf16x8*)(WtF + (size_t)tid * 8) = o.v;
}

// ---------------- adjpack: adj -> transposed bit groups ----------------
// pT layout: uint4 at pT4[w4 * NN + i] = words {w4*4 .. w4*4+3} of row i
// (word w covers j = w*32 .. w*32+31, bit = j&31).
__global__ __launch_bounds__(256) void adjpack(const int* __restrict__ adj,
                                               unsigned* __restrict__ pT) {
    int gw   = (blockIdx.x * 256 + threadIdx.x) >> 6;  // global wave
    int lane = threadIdx.x & 63;
    int i = gw >> 4, seg = gw & 15;                    // 16 segs x 256 j
    const int* ap = adj + (size_t)i * NN + seg * 256 + lane;
    unsigned long long b0 = __ballot(ap[0]   != 0);
    unsigned long long b1 = __ballot(ap[64]  != 0);
    unsigned long long b2 = __ballot(ap[128] != 0);
    unsigned long long b3 = __ballot(ap[192] != 0);
    if (lane == 0) {
        *(uint4*)(pT + ((size_t)(seg * 2    ) * NN + i) * 4) =
            make_uint4((unsigned)b0, (unsigned)(b0 >> 32), (unsigned)b1, (unsigned)(b1 >> 32));
        *(uint4*)(pT + ((size_t)(seg * 2 + 1) * NN + i) * 4) =
            make_uint4((unsigned)b2, (unsigned)(b2 >> 32), (unsigned)b3, (unsigned)(b3 >> 32));
    }
}

// ---------------- gemm: h = x@W -> VtF (B-fragment order) ----------------
// grid (64,8): bx = 64 j-rows (4 waves x 16), by: hd = by>>1, nt-pair = (by&1)*2.
__global__ __launch_bounds__(256) void gemm(const short* __restrict__ xb,
                                            const short* __restrict__ WtF,
                                            short* __restrict__ VtF) {
    const int lane = threadIdx.x & 63, wv = threadIdx.x >> 6;
    const int q = lane >> 4, r = lane & 15;
    const int i0 = blockIdx.x * 64 + wv * 16;
    const int hd = blockIdx.y >> 1, ntp = (blockIdx.y & 1) * 2;

    const short* xp = xb + (size_t)(i0 + r) * KF + q * 8;
    const short* wp = WtF + ((size_t)((hd * 4 + ntp) * 64 + lane)) * 8;

    f32x4 acc0 = {}, acc1 = {};
    #pragma unroll
    for (int kb = 0; kb < 16; kb++) {
        bf16x8 av = *(const bf16x8*)(xp + kb * 32);
        bf16x8 b0 = *(const bf16x8*)(wp + kb * 8192);
        bf16x8 b1 = *(const bf16x8*)(wp + kb * 8192 + 512);
        acc0 = __builtin_amdgcn_mfma_f32_16x16x32_bf16(av, b0, acc0, 0, 0, 0);
        acc1 = __builtin_amdgcn_mfma_f32_16x16x32_bf16(av, b1, acc1, 0, 0, 0);
    }
    // lane holds h[j=i0+q*4+reg][n=base_n+r]; write into fragment slot:
    // j-offset-in-32 = (i0&16)+q*4+reg -> qa = >>3, e0 = &7 (0 or 4)
    const int jblk = i0 >> 5;
    const int base = (i0 & 16) + q * 4;
    const int qa = base >> 3, e0 = base & 7;
    ST4 s0, s1;
    s0.h[0] = pkbf(acc0[0], acc0[1]); s0.h[1] = pkbf(acc0[2], acc0[3]);
    s1.h[0] = pkbf(acc1[0], acc1[1]); s1.h[1] = pkbf(acc1[2], acc1[3]);
    *(s16x4*)(VtF + ((size_t)(((jblk * 4 + hd) * 4 + ntp    ) * 64 + qa * 16 + r)) * 8 + e0) = s0.v;
    *(s16x4*)(VtF + ((size_t)(((jblk * 4 + hd) * 4 + ntp + 1) * 64 + qa * 16 + r)) * 8 + e0) = s1.v;
}

// ---------------- prep: s,t from VtF -> ipack (c=e^{-0.8s}), jpack (e^t, e^{0.2t}) ----------------
// grid 128 (jblk), block 256: wave = head. lane l holds h[j=(l>>4)*8+e][f=nt*16+(l&15)].
__global__ __launch_bounds__(256) void prep(const short* __restrict__ VtF,
                                            const float* __restrict__ a,
                                            float* __restrict__ ipk,
                                            float2* __restrict__ jpk) {
    const int l = threadIdx.x & 63, hd = threadIdx.x >> 6;
    const int q = l >> 4, r = l & 15;
    const int jblk = blockIdx.x;
    float as[4], at[4];
    #pragma unroll
    for (int nt = 0; nt < 4; nt++) { as[nt] = a[nt * 16 + r]; at[nt] = a[64 + nt * 16 + r]; }
    float ps[8] = {}, pt[8] = {};
    #pragma unroll
    for (int nt = 0; nt < 4; nt++) {
        AB8 hv; hv.v = *(const bf16x8*)(VtF + ((size_t)(((jblk * 4 + hd) * 4 + nt) * 64 + l)) * 8);
        #pragma unroll
        for (int e = 0; e < 8; e++) { float v = bf2f(hv.s[e]); ps[e] += v * as[nt]; pt[e] += v * at[nt]; }
    }
    #pragma unroll
    for (int d = 1; d < 16; d <<= 1) {
        #pragma unroll
        for (int e = 0; e < 8; e++) { ps[e] += __shfl_xor(ps[e], d, 64); pt[e] += __shfl_xor(pt[e], d, 64); }
    }
    if (r == 0) {
        #pragma unroll
        for (int e = 0; e < 8; e++) {
            int j = jblk * 32 + q * 8 + e;
            ipk[hd * NN + j] = __expf(-0.8f * ps[e]);
            jpk[hd * NN + j] = make_float2(__expf(pt[e]), __expf(0.2f * pt[e]));
        }
    }
}

// ---------------- attn: fused masked softmax + attn@h ----------------
// grid 256 (16 i-rows each), block 1024 = 16 waves: wave = (jq<<2)|hd.
struct PF { float4 ja, jb, jc, jd; int4 v0, v1, v2, v3; };

__global__ __launch_bounds__(1024) __attribute__((amdgpu_waves_per_eu(1, 4)))
void gat_attn(const uint4* __restrict__ pT4, const float* __restrict__ ipk,
              const float* __restrict__ jpkf, const short* __restrict__ VtF,
              float* __restrict__ out) {
    const int tid = threadIdx.x, lane = tid & 63, wv = tid >> 6;
    const int hd = wv & 3, jq = wv >> 2;
    const int q = lane >> 4, r = lane & 15;
    const int i0 = blockIdx.x * 16, i = i0 + r;
    const float ci = ipk[hd * NN + i];          // e^{-0.8 s_i}
    const int qs = q * 8;
    const float* jpf = jpkf + (size_t)hd * NN * 2;

    f32x4 acc[5] = {};
    AB8 ones;
    #pragma unroll
    for (int e = 0; e < 8; e++) ones.s[e] = (short)0x3F80;   // bf16 1.0

    auto load_pf = [&](PF& p, int it) {
        const float4* jp = (const float4*)(jpf + 2 * ((jq << 10) + (it << 5) + qs));
        p.ja = jp[0]; p.jb = jp[1]; p.jc = jp[2]; p.jd = jp[3];
        const int4* vp = (const int4*)(VtF + (size_t)(((jq * 32 + it) * 16 + hd * 4) * 512) + lane * 8);
        p.v0 = vp[0]; p.v1 = vp[64]; p.v2 = vp[128]; p.v3 = vp[192];
    };
    auto consume = [&](const PF& p, unsigned w) {
        float p0 = (w & 1u)   ? fmaxf(p.ja.x, ci * p.ja.y) : 0.f;
        float p1 = (w & 2u)   ? fmaxf(p.ja.z, ci * p.ja.w) : 0.f;
        float p2 = (w & 4u)   ? fmaxf(p.jb.x, ci * p.jb.y) : 0.f;
        float p3 = (w & 8u)   ? fmaxf(p.jb.z, ci * p.jb.w) : 0.f;
        float p4 = (w & 16u)  ? fmaxf(p.jc.x, ci * p.jc.y) : 0.f;
        float p5 = (w & 32u)  ? fmaxf(p.jc.z, ci * p.jc.w) : 0.f;
        float p6 = (w & 64u)  ? fmaxf(p.jd.x, ci * p.jd.y) : 0.f;
        float p7 = (w & 128u) ? fmaxf(p.jd.z, ci * p.jd.w) : 0.f;
        AB8 af;
        af.h[0] = pkbf(p0, p1); af.h[1] = pkbf(p2, p3);
        af.h[2] = pkbf(p4, p5); af.h[3] = pkbf(p6, p7);
        AB8 b0, b1, b2, b3; b0.i4 = p.v0; b1.i4 = p.v1; b2.i4 = p.v2; b3.i4 = p.v3;
        acc[0] = __builtin_amdgcn_mfma_f32_16x16x32_bf16(af.v, b0.v, acc[0], 0, 0, 0);
        acc[1] = __builtin_amdgcn_mfma_f32_16x16x32_bf16(af.v, b1.v, acc[1], 0, 0, 0);
        acc[2] = __builtin_amdgcn_mfma_f32_16x16x32_bf16(af.v, b2.v, acc[2], 0, 0, 0);
        acc[3] = __builtin_amdgcn_mfma_f32_16x16x32_bf16(af.v, b3.v, acc[3], 0, 0, 0);
        acc[4] = __builtin_amdgcn_mfma_f32_16x16x32_bf16(af.v, ones.v, acc[4], 0, 0, 0);
    };

    const uint4* prow = pT4 + (size_t)(jq * 8) * NN + i;   // +NN per word-group
    uint4 wg = prow[0];
    PF pa, pb;
    load_pf(pa, 0);
    #pragma unroll 1
    for (int g = 0; g < 8; g++) {
        uint4 wgn = wg;
        if (g < 7) wgn = prow[(size_t)(g + 1) * NN];
        const int it = g * 4;
        load_pf(pb, it + 1); consume(pa, wg.x >> qs);
        load_pf(pa, it + 2); consume(pb, wg.y >> qs);
        load_pf(pb, it + 3); consume(pa, wg.z >> qs);
        if (g < 7) load_pf(pa, it + 4);
        consume(pb, wg.w >> qs);
        wg = wgn;
    }

    // Combine 4 j-quarters through LDS; rowsum lives in acc[4] (all cols equal).
    __shared__ float sacc[3][4][5][64][4];
    if (jq > 0) {
        const int gg = jq - 1;
        #pragma unroll
        for (int t = 0; t < 5; t++)
            *(f32x4*)&sacc[gg][hd][t][lane][0] = acc[t];
    }
    __syncthreads();
    if (jq == 0) {
        #pragma unroll
        for (int gg = 0; gg < 3; gg++)
            #pragma unroll
            for (int t = 0; t < 5; t++) {
                f32x4 o = *(const f32x4*)&sacc[gg][hd][t][lane][0];
                acc[t][0] += o[0]; acc[t][1] += o[1];
                acc[t][2] += o[2]; acc[t][3] += o[3];
            }
        #pragma unroll
        for (int reg = 0; reg < 4; reg++) {
            float inv = 1.f / acc[4][reg];
            int row = i0 + q * 4 + reg;
            #pragma unroll
            for (int t = 0; t < 4; t++)
                out[(size_t)row * NF + hd * 64 + t * 16 + r] = acc[t][reg] * inv;
        }
    }
}

extern "C" void kernel_launch(void* const* d_in, const int* in_sizes, int n_in,
                              void* d_out, int out_size, void* d_ws, size_t ws_size,
                              hipStream_t stream) {
    const float* x   = (const float*)d_in[0];
    const int*   adj = (const int*)d_in[1];
    const float* W   = (const float*)d_in[2];
    const float* a   = (const float*)d_in[3];
    float* out = (float*)d_out;

    char* ws = (char*)d_ws;
    short*    xb  = (short*)ws;                          // 4 MiB
    short*    WtF = (short*)(ws + 4194304);              // 256 KiB
    short*    VtF = (short*)(ws + 4456448);              // 2 MiB
    unsigned* pT  = (unsigned*)(ws + 6553600);           // 2 MiB
    float*    ipk = (float*)(ws + 8650752);              // 64 KiB
    float2*   jpk = (float2*)(ws + 8716288);             // 128 KiB

    xcast  <<<2048, 256, 0, stream>>>(x, xb);
    wpack  <<<64, 256, 0, stream>>>(W, WtF);
    adjpack<<<16384, 256, 0, stream>>>(adj, pT);
    gemm   <<<dim3(64, 8), 256, 0, stream>>>(xb, WtF, VtF);
    prep   <<<128, 256, 0, stream>>>(VtF, a, ipk, jpk);
    gat_attn<<<256, 1024, 0, stream>>>((const uint4*)pT, ipk, (const float*)jpk, VtF, out);
}